// Round 1
// baseline (228.839 us; speedup 1.0000x reference)
//
#include <hip/hip_runtime.h>
#include <stdint.h>

#define B_ 16
#define L_ 1024
#define D_ 1024
#define H_ 1024
#define R_ 128
#define M_ (B_ * L_) /* 16384 */

using f32x4  = __attribute__((ext_vector_type(4))) float;
using bf16x8 = __attribute__((ext_vector_type(8))) short;

__device__ __forceinline__ short f2bf(float f) {
  uint32_t u = __builtin_bit_cast(uint32_t, f);
  u = (u + 0x7FFFu + ((u >> 16) & 1u)) >> 16;   // RNE
  return (short)(uint16_t)u;
}
__device__ __forceinline__ float bf2f(uint16_t h) {
  return __builtin_bit_cast(float, (uint32_t)h << 16);
}

// ---------------- f32 -> bf16 convert (8 elems/thread, exact grid) -------------
__global__ void k_f32_to_bf16(const float* __restrict__ in, short* __restrict__ out) {
  size_t i = ((size_t)blockIdx.x * blockDim.x + threadIdx.x) * 8;
  float4 a = *(const float4*)(in + i);
  float4 b = *(const float4*)(in + i + 4);
  union { short s[8]; bf16x8 v; } o;
  o.s[0] = f2bf(a.x); o.s[1] = f2bf(a.y); o.s[2] = f2bf(a.z); o.s[3] = f2bf(a.w);
  o.s[4] = f2bf(b.x); o.s[5] = f2bf(b.y); o.s[6] = f2bf(b.z); o.s[7] = f2bf(b.w);
  *(bf16x8*)(out + i) = o.v;
}

// -------- transpose [K][N] f32 -> [N][K] bf16 (64x64 LDS tiles) ---------------
__global__ void k_transpose_bf16(const float* __restrict__ in, short* __restrict__ out,
                                 int K, int N) {
  __shared__ float s[64][65];
  int n0 = blockIdx.x * 64, k0 = blockIdx.y * 64;
  int tx = threadIdx.x & 63, tq = threadIdx.x >> 6;
#pragma unroll
  for (int j = 0; j < 16; ++j) {
    int r = j * 4 + tq;
    s[r][tx] = in[(size_t)(k0 + r) * N + (n0 + tx)];
  }
  __syncthreads();
#pragma unroll
  for (int j = 0; j < 16; ++j) {
    int r = j * 4 + tq;
    out[(size_t)(n0 + r) * K + (k0 + tx)] = f2bf(s[tx][r]);
  }
}

// -------- NT bf16 GEMM, 128x128 tile, BK=32, bias+ReLU, bf16 out --------------
// A [M][K] bf16 row-major, Bt [N][K] bf16 row-major. m97 structure (guide §5).
__global__ __launch_bounds__(256)
void k_gemm_bias_relu(const short* __restrict__ A, const short* __restrict__ Bt,
                      const float* __restrict__ bias, short* __restrict__ C,
                      int M, int N, int K) {
  __shared__ __align__(16) short As[128 * 32];
  __shared__ __align__(16) short Bs[128 * 32];
  const int tid = threadIdx.x, lane = tid & 63, wave = tid >> 6;
  const int wr = wave >> 1, wc = wave & 1;
  const int m0 = blockIdx.y * 128, n0 = blockIdx.x * 128;
  const int lrow = lane & 15, lk8 = (lane >> 4) * 8;
  const int srow = lane >> 2;        // row within 16-row chunk
  const int skc  = (lane & 3) * 8;   // k-element offset within row

  f32x4 acc[4][4] = {};

  for (int k0 = 0; k0 < K; k0 += 32) {
#pragma unroll
    for (int c = 0; c < 2; ++c) {
      int chunk = wave * 2 + c;
      int row = chunk * 16 + srow;
      const short* ga = A  + (size_t)(m0 + row) * K + (k0 + skc);
      const short* gb = Bt + (size_t)(n0 + row) * K + (k0 + skc);
      __builtin_amdgcn_global_load_lds(
          (const __attribute__((address_space(1))) void*)ga,
          (__attribute__((address_space(3))) void*)(As + chunk * 512 + lane * 8), 16, 0, 0);
      __builtin_amdgcn_global_load_lds(
          (const __attribute__((address_space(1))) void*)gb,
          (__attribute__((address_space(3))) void*)(Bs + chunk * 512 + lane * 8), 16, 0, 0);
    }
    __syncthreads();   // drains vmcnt before barrier (compiler-emitted)

    bf16x8 af[4], bfr[4];
#pragma unroll
    for (int m = 0; m < 4; ++m)
      af[m] = *(const bf16x8*)(As + (wr * 64 + m * 16 + lrow) * 32 + lk8);
#pragma unroll
    for (int n = 0; n < 4; ++n)
      bfr[n] = *(const bf16x8*)(Bs + (wc * 64 + n * 16 + lrow) * 32 + lk8);
#pragma unroll
    for (int m = 0; m < 4; ++m)
#pragma unroll
      for (int n = 0; n < 4; ++n)
        acc[m][n] = __builtin_amdgcn_mfma_f32_16x16x32_bf16(af[m], bfr[n], acc[m][n], 0, 0, 0);
    __syncthreads();
  }

  // epilogue: C/D layout col=lane&15, row=(lane>>4)*4+reg  [m89]
  const int rbase = m0 + wr * 64 + (lane >> 4) * 4;
  const int cbase = n0 + wc * 64 + lrow;
#pragma unroll
  for (int n = 0; n < 4; ++n) {
    const int col = cbase + n * 16;
    const float bn = bias[col];
#pragma unroll
    for (int m = 0; m < 4; ++m) {
      const int row = rbase + m * 16;
#pragma unroll
      for (int r = 0; r < 4; ++r) {
        float v = acc[m][n][r] + bn;
        C[(size_t)(row + r) * N + col] = f2bf(fmaxf(v, 0.f));
      }
    }
  }
}

// -------- row squared-norms of T [M][R] bf16 -> sq [M] f32 (wave per row) -----
__global__ void k_rowsq(const short* __restrict__ T, float* __restrict__ sq) {
  int row  = blockIdx.x * 4 + (threadIdx.x >> 6);
  int lane = threadIdx.x & 63;
  uint32_t u = *(const uint32_t*)(T + (size_t)row * R_ + lane * 2);
  float a = bf2f((uint16_t)(u & 0xffffu));
  float b = bf2f((uint16_t)(u >> 16));
  float s = a * a + b * b;
#pragma unroll
  for (int o = 32; o >= 1; o >>= 1) s += __shfl_xor(s, o, 64);
  if (lane == 0) sq[row] = s;
}

// -------- per-batch pairwise: out = max(sq_i + sq_j - 2*T_i.T_j, 0) -----------
__global__ __launch_bounds__(256)
void k_pairwise(const short* __restrict__ T, const float* __restrict__ sq,
                float* __restrict__ out) {
  __shared__ __align__(16) short As[128 * 32];
  __shared__ __align__(16) short Bs[128 * 32];
  const int b = blockIdx.z;
  const short* Tb  = T  + (size_t)b * L_ * R_;
  const float* sqb = sq + (size_t)b * L_;
  const int tid = threadIdx.x, lane = tid & 63, wave = tid >> 6;
  const int wr = wave >> 1, wc = wave & 1;
  const int m0 = blockIdx.y * 128, n0 = blockIdx.x * 128;
  const int lrow = lane & 15, lk8 = (lane >> 4) * 8;
  const int srow = lane >> 2;
  const int skc  = (lane & 3) * 8;

  f32x4 acc[4][4] = {};

  for (int k0 = 0; k0 < R_; k0 += 32) {
#pragma unroll
    for (int c = 0; c < 2; ++c) {
      int chunk = wave * 2 + c;
      int row = chunk * 16 + srow;
      const short* ga = Tb + (size_t)(m0 + row) * R_ + (k0 + skc);
      const short* gb = Tb + (size_t)(n0 + row) * R_ + (k0 + skc);
      __builtin_amdgcn_global_load_lds(
          (const __attribute__((address_space(1))) void*)ga,
          (__attribute__((address_space(3))) void*)(As + chunk * 512 + lane * 8), 16, 0, 0);
      __builtin_amdgcn_global_load_lds(
          (const __attribute__((address_space(1))) void*)gb,
          (__attribute__((address_space(3))) void*)(Bs + chunk * 512 + lane * 8), 16, 0, 0);
    }
    __syncthreads();

    bf16x8 af[4], bfr[4];
#pragma unroll
    for (int m = 0; m < 4; ++m)
      af[m] = *(const bf16x8*)(As + (wr * 64 + m * 16 + lrow) * 32 + lk8);
#pragma unroll
    for (int n = 0; n < 4; ++n)
      bfr[n] = *(const bf16x8*)(Bs + (wc * 64 + n * 16 + lrow) * 32 + lk8);
#pragma unroll
    for (int m = 0; m < 4; ++m)
#pragma unroll
      for (int n = 0; n < 4; ++n)
        acc[m][n] = __builtin_amdgcn_mfma_f32_16x16x32_bf16(af[m], bfr[n], acc[m][n], 0, 0, 0);
    __syncthreads();
  }

  const int rbase = m0 + wr * 64 + (lane >> 4) * 4;
  const int cbase = n0 + wc * 64 + lrow;
  float sqj[4];
#pragma unroll
  for (int n = 0; n < 4; ++n) sqj[n] = sqb[cbase + n * 16];
#pragma unroll
  for (int m = 0; m < 4; ++m) {
#pragma unroll
    for (int r = 0; r < 4; ++r) {
      const int row = rbase + m * 16 + r;
      const float sqi = sqb[row];
      float* orow = out + ((size_t)b * L_ + row) * L_;
#pragma unroll
      for (int n = 0; n < 4; ++n) {
        float d = sqi + sqj[n] - 2.0f * acc[m][n][r];
        orow[cbase + n * 16] = fmaxf(d, 0.f);
      }
    }
  }
}

extern "C" void kernel_launch(void* const* d_in, const int* in_sizes, int n_in,
                              void* d_out, int out_size, void* d_ws, size_t ws_size,
                              hipStream_t stream) {
  const float* X  = (const float*)d_in[0];
  const float* W1 = (const float*)d_in[1];
  const float* b1 = (const float*)d_in[2];
  const float* W2 = (const float*)d_in[3];
  const float* b2 = (const float*)d_in[4];
  float* out = (float*)d_out;

  char* ws = (char*)d_ws;
  size_t off = 0;
  auto alloc = [&](size_t bytes) {
    char* p = ws + off;
    off += (bytes + 255) & ~(size_t)255;
    return p;
  };
  short* Xb  = (short*)alloc((size_t)M_ * D_ * 2);  // X in bf16
  short* W1t = (short*)alloc((size_t)H_ * D_ * 2);  // W1^T bf16 [H][D]
  short* Hb  = (short*)alloc((size_t)M_ * H_ * 2);  // h bf16
  short* W2t = (short*)alloc((size_t)R_ * H_ * 2);  // W2^T bf16 [R][H]
  short* Tb  = (short*)alloc((size_t)M_ * R_ * 2);  // t bf16
  float* Sq  = (float*)alloc((size_t)M_ * 4);       // row norms f32

  k_f32_to_bf16<<<((size_t)M_ * D_) / 2048, 256, 0, stream>>>(X, Xb);
  k_transpose_bf16<<<dim3(H_ / 64, D_ / 64), 256, 0, stream>>>(W1, W1t, D_, H_);
  k_transpose_bf16<<<dim3(R_ / 64, H_ / 64), 256, 0, stream>>>(W2, W2t, H_, R_);
  k_gemm_bias_relu<<<dim3(H_ / 128, M_ / 128), 256, 0, stream>>>(Xb, W1t, b1, Hb, M_, H_, D_);
  k_gemm_bias_relu<<<dim3(R_ / 128, M_ / 128), 256, 0, stream>>>(Hb, W2t, b2, Tb, M_, R_, H_);
  k_rowsq<<<M_ / 4, 256, 0, stream>>>(Tb, Sq);
  k_pairwise<<<dim3(L_ / 128, L_ / 128, B_), 256, 0, stream>>>(Tb, Sq, out);
}

// Round 3
// 209.569 us; speedup vs baseline: 1.0919x; 1.0919x over previous
//
#include <hip/hip_runtime.h>
#include <stdint.h>

#define B_ 16
#define L_ 1024
#define D_ 1024
#define H_ 1024
#define R_ 128
#define M_ (B_ * L_) /* 16384 */

using f32x4  = __attribute__((ext_vector_type(4))) float;
using bf16x8 = __attribute__((ext_vector_type(8))) short;

__device__ __forceinline__ short f2bf(float f) {
  uint32_t u = __builtin_bit_cast(uint32_t, f);
  u = (u + 0x7FFFu + ((u >> 16) & 1u)) >> 16;   // RNE
  return (short)(uint16_t)u;
}
__device__ __forceinline__ float bf2f(uint16_t h) {
  return __builtin_bit_cast(float, (uint32_t)h << 16);
}

// ---------------- f32 -> bf16 convert (8 elems/thread) ------------------------
__global__ void k_f32_to_bf16(const float* __restrict__ in, short* __restrict__ out) {
  size_t i = ((size_t)blockIdx.x * blockDim.x + threadIdx.x) * 8;
  float4 a = *(const float4*)(in + i);
  float4 b = *(const float4*)(in + i + 4);
  union { short s[8]; bf16x8 v; } o;
  o.s[0] = f2bf(a.x); o.s[1] = f2bf(a.y); o.s[2] = f2bf(a.z); o.s[3] = f2bf(a.w);
  o.s[4] = f2bf(b.x); o.s[5] = f2bf(b.y); o.s[6] = f2bf(b.z); o.s[7] = f2bf(b.w);
  *(bf16x8*)(out + i) = o.v;
}

// -------- transpose [K][N] f32 -> [N][K] bf16 (64x64 LDS tiles) ---------------
__global__ void k_transpose_bf16(const float* __restrict__ in, short* __restrict__ out,
                                 int K, int N) {
  __shared__ float s[64][65];
  int n0 = blockIdx.x * 64, k0 = blockIdx.y * 64;
  int tx = threadIdx.x & 63, tq = threadIdx.x >> 6;
#pragma unroll
  for (int j = 0; j < 16; ++j) {
    int r = j * 4 + tq;
    s[r][tx] = in[(size_t)(k0 + r) * N + (n0 + tx)];
  }
  __syncthreads();
#pragma unroll
  for (int j = 0; j < 16; ++j) {
    int r = j * 4 + tq;
    out[(size_t)(n0 + r) * K + (k0 + tx)] = f2bf(s[tx][r]);
  }
}

// ---- shared 128x128-tile MFMA main loop (m97 structure, NT bf16, BK=32) ------
// Ap: A + m0*ld (+kOff), Bp: Bt + n0*ld (+kOff); both row-major, row stride ld.
__device__ __forceinline__ void gemm_body_128(const short* __restrict__ Ap,
                                              const short* __restrict__ Bp,
                                              int ld, int kSteps,
                                              short* As, short* Bs,
                                              f32x4 (&acc)[4][4]) {
  const int tid = threadIdx.x, lane = tid & 63, wave = tid >> 6;
  const int wr = wave >> 1, wc = wave & 1;
  const int lrow = lane & 15, lk8 = (lane >> 4) * 8;
  const int srow = lane >> 2;        // row within 16-row chunk
  const int skc  = (lane & 3) * 8;   // k-element offset within row

  for (int ks = 0; ks < kSteps; ++ks) {
    const int k0 = ks * 32;
#pragma unroll
    for (int c = 0; c < 2; ++c) {
      int chunk = wave * 2 + c;
      int row = chunk * 16 + srow;
      const short* ga = Ap + (size_t)row * ld + (k0 + skc);
      const short* gb = Bp + (size_t)row * ld + (k0 + skc);
      __builtin_amdgcn_global_load_lds(
          (const __attribute__((address_space(1))) void*)ga,
          (__attribute__((address_space(3))) void*)(As + chunk * 512 + lane * 8), 16, 0, 0);
      __builtin_amdgcn_global_load_lds(
          (const __attribute__((address_space(1))) void*)gb,
          (__attribute__((address_space(3))) void*)(Bs + chunk * 512 + lane * 8), 16, 0, 0);
    }
    __syncthreads();

    bf16x8 af[4], bfr[4];
#pragma unroll
    for (int m = 0; m < 4; ++m)
      af[m] = *(const bf16x8*)(As + (wr * 64 + m * 16 + lrow) * 32 + lk8);
#pragma unroll
    for (int n = 0; n < 4; ++n)
      bfr[n] = *(const bf16x8*)(Bs + (wc * 64 + n * 16 + lrow) * 32 + lk8);
#pragma unroll
    for (int m = 0; m < 4; ++m)
#pragma unroll
      for (int n = 0; n < 4; ++n)
        acc[m][n] = __builtin_amdgcn_mfma_f32_16x16x32_bf16(af[m], bfr[n], acc[m][n], 0, 0, 0);
    __syncthreads();
  }
}

// -------- GEMM1: M=16384 N=1024 K=1024, XCD-swizzled grid (1024 blocks) -------
// 2-level swizzle: each XCD gets groups of 64 blocks = 8 m-tiles x all 8 n-tiles
// -> per-XCD working set A 2MB + B 2MB = one 4MB L2.
__global__ __launch_bounds__(256)
void k_gemm1(const short* __restrict__ A, const short* __restrict__ Bt,
             const float* __restrict__ bias, short* __restrict__ C) {
  __shared__ __align__(16) short As[128 * 32];
  __shared__ __align__(16) short Bs[128 * 32];
  const int b = blockIdx.x;
  const int xcd = b & 7, seq = b >> 3;
  const int g = xcd + ((seq >> 6) << 3);   // 0..15
  const int i = seq & 63;
  const int m0 = (g * 8 + (i >> 3)) * 128; // 0..127 tiles
  const int n0 = (i & 7) * 128;            // 0..7 tiles

  f32x4 acc[4][4] = {};
  gemm_body_128(A + (size_t)m0 * D_, Bt + (size_t)n0 * D_, D_, D_ / 32, As, Bs, acc);

  const int lane = threadIdx.x & 63, wave = threadIdx.x >> 6;
  const int wr = wave >> 1, wc = wave & 1;
  const int rbase = m0 + wr * 64 + (lane >> 4) * 4;
  const int cbase = n0 + wc * 64 + (lane & 15);
#pragma unroll
  for (int n = 0; n < 4; ++n) {
    const int col = cbase + n * 16;
    const float bn = bias[col];
#pragma unroll
    for (int m = 0; m < 4; ++m) {
      const int row = rbase + m * 16;
#pragma unroll
      for (int r = 0; r < 4; ++r) {
        float v = acc[m][n][r] + bn;
        C[(size_t)(row + r) * H_ + col] = f2bf(fmaxf(v, 0.f));
      }
    }
  }
}

// -------- GEMM2 split-K=4: M=16384 N=128 K=1024 -> f32 partials ---------------
__global__ __launch_bounds__(256)
void k_gemm2_splitk(const short* __restrict__ A, const short* __restrict__ Bt,
                    float* __restrict__ P) {
  __shared__ __align__(16) short As[128 * 32];
  __shared__ __align__(16) short Bs[128 * 32];
  const int m0 = blockIdx.y * 128;
  const int s  = blockIdx.z;
  const int kOff = s * (H_ / 4);

  f32x4 acc[4][4] = {};
  gemm_body_128(A + (size_t)m0 * H_ + kOff, Bt + kOff, H_, (H_ / 4) / 32, As, Bs, acc);

  const int lane = threadIdx.x & 63, wave = threadIdx.x >> 6;
  const int wr = wave >> 1, wc = wave & 1;
  const int rbase = wr * 64 + (lane >> 4) * 4;
  const int cbase = wc * 64 + (lane & 15);
  float* Ps = P + (size_t)s * M_ * R_ + (size_t)m0 * R_;
#pragma unroll
  for (int m = 0; m < 4; ++m)
#pragma unroll
    for (int r = 0; r < 4; ++r)
#pragma unroll
      for (int n = 0; n < 4; ++n)
        Ps[(size_t)(rbase + m * 16 + r) * R_ + cbase + n * 16] = acc[m][n][r];
}

// -------- reduce split-K partials + bias + ReLU -> bf16 T, fused row norms ----
__global__ void k_reduce2(const float* __restrict__ P, const float* __restrict__ b2,
                          short* __restrict__ T, float* __restrict__ sq) {
  const int row  = blockIdx.x * 4 + (threadIdx.x >> 6);
  const int lane = threadIdx.x & 63;
  const int c0 = lane * 2;
  float s0 = 0.f, s1 = 0.f;
#pragma unroll
  for (int s = 0; s < 4; ++s) {
    const float2 v = *(const float2*)(P + ((size_t)s * M_ + row) * R_ + c0);
    s0 += v.x; s1 += v.y;
  }
  float v0 = fmaxf(s0 + b2[c0], 0.f);
  float v1 = fmaxf(s1 + b2[c0 + 1], 0.f);
  uint32_t pk = (uint32_t)(uint16_t)f2bf(v0) | ((uint32_t)(uint16_t)f2bf(v1) << 16);
  *(uint32_t*)(T + (size_t)row * R_ + c0) = pk;
  float q = v0 * v0 + v1 * v1;
#pragma unroll
  for (int o = 32; o >= 1; o >>= 1) q += __shfl_xor(q, o, 64);
  if (lane == 0) sq[row] = q;
}

// -------- per-batch pairwise: out = max(sq_i + sq_j - 2*T_i.T_j, 0) -----------
__global__ __launch_bounds__(256)
void k_pairwise(const short* __restrict__ T, const float* __restrict__ sq,
                float* __restrict__ out) {
  __shared__ __align__(16) short As[128 * 32];
  __shared__ __align__(16) short Bs[128 * 32];
  const int b = blockIdx.z;
  const short* Tb  = T  + (size_t)b * L_ * R_;
  const float* sqb = sq + (size_t)b * L_;
  const int m0 = blockIdx.y * 128, n0 = blockIdx.x * 128;

  f32x4 acc[4][4] = {};
  gemm_body_128(Tb + (size_t)m0 * R_, Tb + (size_t)n0 * R_, R_, R_ / 32, As, Bs, acc);

  const int lane = threadIdx.x & 63, wave = threadIdx.x >> 6;
  const int wr = wave >> 1, wc = wave & 1;
  const int rbase = m0 + wr * 64 + (lane >> 4) * 4;
  const int cbase = n0 + wc * 64 + (lane & 15);
  float sqj[4];
#pragma unroll
  for (int n = 0; n < 4; ++n) sqj[n] = sqb[cbase + n * 16];
#pragma unroll
  for (int m = 0; m < 4; ++m) {
#pragma unroll
    for (int r = 0; r < 4; ++r) {
      const int row = rbase + m * 16 + r;
      const float sqi = sqb[row];
      float* orow = out + ((size_t)b * L_ + row) * L_;
#pragma unroll
      for (int n = 0; n < 4; ++n) {
        float d = sqi + sqj[n] - 2.0f * acc[m][n][r];
        orow[cbase + n * 16] = fmaxf(d, 0.f);
      }
    }
  }
}

extern "C" void kernel_launch(void* const* d_in, const int* in_sizes, int n_in,
                              void* d_out, int out_size, void* d_ws, size_t ws_size,
                              hipStream_t stream) {
  const float* X  = (const float*)d_in[0];
  const float* W1 = (const float*)d_in[1];
  const float* b1 = (const float*)d_in[2];
  const float* W2 = (const float*)d_in[3];
  const float* b2 = (const float*)d_in[4];
  float* out = (float*)d_out;

  char* ws = (char*)d_ws;
  size_t off = 0;
  auto alloc = [&](size_t bytes) {
    char* p = ws + off;
    off += (bytes + 255) & ~(size_t)255;
    return p;
  };
  short* Xb  = (short*)alloc((size_t)M_ * D_ * 2);  // X bf16 (dead after GEMM1)
  short* W1t = (short*)alloc((size_t)H_ * D_ * 2);  // W1^T bf16 [H][D]
  short* Hb  = (short*)alloc((size_t)M_ * H_ * 2);  // h bf16
  short* W2t = (short*)alloc((size_t)R_ * H_ * 2);  // W2^T bf16 [R][H]
  short* Tb  = (short*)alloc((size_t)M_ * R_ * 2);  // t bf16
  float* Sq  = (float*)alloc((size_t)M_ * 4);       // row norms f32
  // split-K partials alias the dead Xb region: 4*M*R*4 B == M*D*2 B exactly
  float* P   = (float*)Xb;

  k_f32_to_bf16<<<((size_t)M_ * D_) / 2048, 256, 0, stream>>>(X, Xb);
  k_transpose_bf16<<<dim3(H_ / 64, D_ / 64), 256, 0, stream>>>(W1, W1t, D_, H_);
  k_transpose_bf16<<<dim3(R_ / 64, H_ / 64), 256, 0, stream>>>(W2, W2t, H_, R_);
  k_gemm1<<<dim3((M_ / 128) * (H_ / 128)), 256, 0, stream>>>(Xb, W1t, b1, Hb);
  k_gemm2_splitk<<<dim3(1, M_ / 128, 4), 256, 0, stream>>>(Hb, W2t, P);
  k_reduce2<<<M_ / 4, 256, 0, stream>>>(P, b2, Tb, Sq);
  k_pairwise<<<dim3(L_ / 128, L_ / 128, B_), 256, 0, stream>>>(Tb, Sq, out);
}

// Round 4
// 204.391 us; speedup vs baseline: 1.1196x; 1.0253x over previous
//
#include <hip/hip_runtime.h>
#include <stdint.h>

#define B_ 16
#define L_ 1024
#define D_ 1024
#define H_ 1024
#define R_ 128
#define M_ (B_ * L_) /* 16384 */

using f32x4  = __attribute__((ext_vector_type(4))) float;
using bf16x8 = __attribute__((ext_vector_type(8))) short;

__device__ __forceinline__ short f2bf(float f) {
  uint32_t u = __builtin_bit_cast(uint32_t, f);
  u = (u + 0x7FFFu + ((u >> 16) & 1u)) >> 16;   // RNE
  return (short)(uint16_t)u;
}
__device__ __forceinline__ float bf2f(uint16_t h) {
  return __builtin_bit_cast(float, (uint32_t)h << 16);
}

// inline-asm LDS read: avoids compiler-inserted conservative waits; pairs with
// explicit lgkmcnt(0) + sched_barrier(0) before MFMA use (guide rule #18).
__device__ __forceinline__ bf16x8 lds_read_frag(const short* base, int elemOff) {
  bf16x8 r;
  const __attribute__((address_space(3))) short* p =
      (const __attribute__((address_space(3))) short*)(base) + elemOff;
  asm volatile("ds_read_b128 %0, %1" : "=v"(r) : "v"((uint32_t)(uintptr_t)p));
  return r;
}

// ---------------- fused prep: X f32->bf16 + W1^T + W2^T -----------------------
#define CONV_BLKS 8192   /* M_*D_/2048 */
#define T1B 256          /* (H_/64)*(D_/64) */
#define T2B 32           /* (R_/64)*(H_/64) */
__global__ void k_prep(const float* __restrict__ X, const float* __restrict__ W1,
                       const float* __restrict__ W2, short* __restrict__ Xb,
                       short* __restrict__ W1t, short* __restrict__ W2t) {
  __shared__ float s[64][65];
  const int b = blockIdx.x;
  if (b < CONV_BLKS) {
    size_t i = ((size_t)b * 256 + threadIdx.x) * 8;
    float4 a = *(const float4*)(X + i);
    float4 c = *(const float4*)(X + i + 4);
    union { short sh[8]; bf16x8 v; } o;
    o.sh[0] = f2bf(a.x); o.sh[1] = f2bf(a.y); o.sh[2] = f2bf(a.z); o.sh[3] = f2bf(a.w);
    o.sh[4] = f2bf(c.x); o.sh[5] = f2bf(c.y); o.sh[6] = f2bf(c.z); o.sh[7] = f2bf(c.w);
    *(bf16x8*)(Xb + i) = o.v;
    return;
  }
  const float* in; short* out; int K, N, bx, by;
  if (b < CONV_BLKS + T1B) {
    int t = b - CONV_BLKS; in = W1; out = W1t; K = D_; N = H_; bx = t & 15; by = t >> 4;
  } else {
    int t = b - CONV_BLKS - T1B; in = W2; out = W2t; K = H_; N = R_; bx = t & 1; by = t >> 1;
  }
  const int n0 = bx * 64, k0 = by * 64;
  const int tx = threadIdx.x & 63, tq = threadIdx.x >> 6;
#pragma unroll
  for (int j = 0; j < 16; ++j) {
    int r = j * 4 + tq;
    s[r][tx] = in[(size_t)(k0 + r) * N + (n0 + tx)];
  }
  __syncthreads();
#pragma unroll
  for (int j = 0; j < 16; ++j) {
    int r = j * 4 + tq;
    out[(size_t)(n0 + r) * K + (k0 + tx)] = f2bf(s[tx][r]);
  }
}

// ---- shared 128x128-tile MFMA loop: double-buffered LDS + counted vmcnt ------
// As/Bs: 2 x 4096 shorts (8KB) each. Iter k computes buf k&1, stages k+1 into
// buf (k+1)&1 (safe: that buf's reads finished before iter k-1's end barrier).
// vmcnt(4) = this iter's 4 staged loads stay in flight; prev tile's 4 (older)
// must have landed. Never drains to 0 mid-loop (T4).
__device__ __forceinline__ void gemm_body_128_db(const short* __restrict__ Ap,
                                                 const short* __restrict__ Bp,
                                                 int ld, int kSteps,
                                                 short* As, short* Bs,
                                                 f32x4 (&acc)[4][4]) {
  const int tid = threadIdx.x, lane = tid & 63, wave = tid >> 6;
  const int wr = wave >> 1, wc = wave & 1;
  const int lrow = lane & 15, lk8 = (lane >> 4) * 8;
  const int srow = lane >> 2;        // row within 16-row chunk
  const int skc  = (lane & 3) * 8;   // k-element offset within row

  auto STAGE = [&](int ks, int d) {
    const int k0 = ks * 32;
#pragma unroll
    for (int c = 0; c < 2; ++c) {
      const int chunk = wave * 2 + c;
      const int row = chunk * 16 + srow;
      __builtin_amdgcn_global_load_lds(
          (const __attribute__((address_space(1))) void*)(Ap + (size_t)row * ld + (k0 + skc)),
          (__attribute__((address_space(3))) void*)(As + d * 4096 + chunk * 512 + lane * 8), 16, 0, 0);
      __builtin_amdgcn_global_load_lds(
          (const __attribute__((address_space(1))) void*)(Bp + (size_t)row * ld + (k0 + skc)),
          (__attribute__((address_space(3))) void*)(Bs + d * 4096 + chunk * 512 + lane * 8), 16, 0, 0);
    }
  };

  STAGE(0, 0);
  for (int ks = 0; ks < kSteps; ++ks) {
    const int cur = ks & 1;
    if (ks + 1 < kSteps) {
      STAGE(ks + 1, cur ^ 1);
      asm volatile("s_waitcnt vmcnt(4)" ::: "memory");
    } else {
      asm volatile("s_waitcnt vmcnt(0)" ::: "memory");
    }
    __builtin_amdgcn_s_barrier();          // tile ks fully in LDS for all waves
    asm volatile("" ::: "memory");

    bf16x8 af[4], bfr[4];
#pragma unroll
    for (int m = 0; m < 4; ++m)
      af[m] = lds_read_frag(As, cur * 4096 + (wr * 64 + m * 16 + lrow) * 32 + lk8);
#pragma unroll
    for (int n = 0; n < 4; ++n)
      bfr[n] = lds_read_frag(Bs, cur * 4096 + (wc * 64 + n * 16 + lrow) * 32 + lk8);
    asm volatile("s_waitcnt lgkmcnt(0)" ::: "memory");
    __builtin_amdgcn_sched_barrier(0);     // rule #18: keep MFMA below the wait
    __builtin_amdgcn_s_setprio(1);
#pragma unroll
    for (int m = 0; m < 4; ++m)
#pragma unroll
      for (int n = 0; n < 4; ++n)
        acc[m][n] = __builtin_amdgcn_mfma_f32_16x16x32_bf16(af[m], bfr[n], acc[m][n], 0, 0, 0);
    __builtin_amdgcn_s_setprio(0);
    asm volatile("" ::: "memory");
    __builtin_amdgcn_s_barrier();          // all reads of buf cur done
  }
}

// -------- GEMM1: M=16384 N=1024 K=1024, XCD-swizzled grid (1024 blocks) -------
__global__ __launch_bounds__(256)
void k_gemm1(const short* __restrict__ A, const short* __restrict__ Bt,
             const float* __restrict__ bias, short* __restrict__ C) {
  __shared__ __align__(16) short As[2 * 4096];
  __shared__ __align__(16) short Bs[2 * 4096];
  const int b = blockIdx.x;
  const int xcd = b & 7, seq = b >> 3;
  const int g = xcd + ((seq >> 6) << 3);   // 0..15
  const int i = seq & 63;
  const int m0 = (g * 8 + (i >> 3)) * 128;
  const int n0 = (i & 7) * 128;

  f32x4 acc[4][4] = {};
  gemm_body_128_db(A + (size_t)m0 * D_, Bt + (size_t)n0 * D_, D_, D_ / 32, As, Bs, acc);

  const int lane = threadIdx.x & 63, wave = threadIdx.x >> 6;
  const int wr = wave >> 1, wc = wave & 1;
  const int rbase = m0 + wr * 64 + (lane >> 4) * 4;
  const int cbase = n0 + wc * 64 + (lane & 15);
#pragma unroll
  for (int n = 0; n < 4; ++n) {
    const int col = cbase + n * 16;
    const float bn = bias[col];
#pragma unroll
    for (int m = 0; m < 4; ++m) {
      const int row = rbase + m * 16;
#pragma unroll
      for (int r = 0; r < 4; ++r) {
        float v = acc[m][n][r] + bn;
        C[(size_t)(row + r) * H_ + col] = f2bf(fmaxf(v, 0.f));
      }
    }
  }
}

// -------- GEMM2 split-K=4: M=16384 N=128 K=1024 -> f32 partials ---------------
__global__ __launch_bounds__(256)
void k_gemm2_splitk(const short* __restrict__ A, const short* __restrict__ Bt,
                    float* __restrict__ P) {
  __shared__ __align__(16) short As[2 * 4096];
  __shared__ __align__(16) short Bs[2 * 4096];
  const int m0 = blockIdx.y * 128;
  const int s  = blockIdx.z;
  const int kOff = s * (H_ / 4);

  f32x4 acc[4][4] = {};
  gemm_body_128_db(A + (size_t)m0 * H_ + kOff, Bt + kOff, H_, (H_ / 4) / 32, As, Bs, acc);

  const int lane = threadIdx.x & 63, wave = threadIdx.x >> 6;
  const int wr = wave >> 1, wc = wave & 1;
  const int rbase = wr * 64 + (lane >> 4) * 4;
  const int cbase = wc * 64 + (lane & 15);
  float* Ps = P + (size_t)s * M_ * R_ + (size_t)m0 * R_;
#pragma unroll
  for (int m = 0; m < 4; ++m)
#pragma unroll
    for (int r = 0; r < 4; ++r)
#pragma unroll
      for (int n = 0; n < 4; ++n)
        Ps[(size_t)(rbase + m * 16 + r) * R_ + cbase + n * 16] = acc[m][n][r];
}

// -------- reduce split-K partials + bias + ReLU -> bf16 T, fused row norms ----
__global__ void k_reduce2(const float* __restrict__ P, const float* __restrict__ b2,
                          short* __restrict__ T, float* __restrict__ sq) {
  const int row  = blockIdx.x * 4 + (threadIdx.x >> 6);
  const int lane = threadIdx.x & 63;
  const int c0 = lane * 2;
  float s0 = 0.f, s1 = 0.f;
#pragma unroll
  for (int s = 0; s < 4; ++s) {
    const float2 v = *(const float2*)(P + ((size_t)s * M_ + row) * R_ + c0);
    s0 += v.x; s1 += v.y;
  }
  float v0 = fmaxf(s0 + b2[c0], 0.f);
  float v1 = fmaxf(s1 + b2[c0 + 1], 0.f);
  uint32_t pk = (uint32_t)(uint16_t)f2bf(v0) | ((uint32_t)(uint16_t)f2bf(v1) << 16);
  *(uint32_t*)(T + (size_t)row * R_ + c0) = pk;
  float q = v0 * v0 + v1 * v1;
#pragma unroll
  for (int o = 32; o >= 1; o >>= 1) q += __shfl_xor(q, o, 64);
  if (lane == 0) sq[row] = q;
}

// -------- per-batch pairwise: out = max(sq_i + sq_j - 2*T_i.T_j, 0) -----------
__global__ __launch_bounds__(256)
void k_pairwise(const short* __restrict__ T, const float* __restrict__ sq,
                float* __restrict__ out) {
  __shared__ __align__(16) short As[2 * 4096];
  __shared__ __align__(16) short Bs[2 * 4096];
  const int b = blockIdx.z;
  const short* Tb  = T  + (size_t)b * L_ * R_;
  const float* sqb = sq + (size_t)b * L_;
  const int m0 = blockIdx.y * 128, n0 = blockIdx.x * 128;

  f32x4 acc[4][4] = {};
  gemm_body_128_db(Tb + (size_t)m0 * R_, Tb + (size_t)n0 * R_, R_, R_ / 32, As, Bs, acc);

  const int lane = threadIdx.x & 63, wave = threadIdx.x >> 6;
  const int wr = wave >> 1, wc = wave & 1;
  const int rbase = m0 + wr * 64 + (lane >> 4) * 4;
  const int cbase = n0 + wc * 64 + (lane & 15);
  float sqj[4];
#pragma unroll
  for (int n = 0; n < 4; ++n) sqj[n] = sqb[cbase + n * 16];
#pragma unroll
  for (int m = 0; m < 4; ++m) {
#pragma unroll
    for (int r = 0; r < 4; ++r) {
      const int row = rbase + m * 16 + r;
      const float sqi = sqb[row];
      float* orow = out + ((size_t)b * L_ + row) * L_;
#pragma unroll
      for (int n = 0; n < 4; ++n) {
        float d = sqi + sqj[n] - 2.0f * acc[m][n][r];
        orow[cbase + n * 16] = fmaxf(d, 0.f);
      }
    }
  }
}

extern "C" void kernel_launch(void* const* d_in, const int* in_sizes, int n_in,
                              void* d_out, int out_size, void* d_ws, size_t ws_size,
                              hipStream_t stream) {
  const float* X  = (const float*)d_in[0];
  const float* W1 = (const float*)d_in[1];
  const float* b1 = (const float*)d_in[2];
  const float* W2 = (const float*)d_in[3];
  const float* b2 = (const float*)d_in[4];
  float* out = (float*)d_out;

  char* ws = (char*)d_ws;
  size_t off = 0;
  auto alloc = [&](size_t bytes) {
    char* p = ws + off;
    off += (bytes + 255) & ~(size_t)255;
    return p;
  };
  short* Xb  = (short*)alloc((size_t)M_ * D_ * 2);  // X bf16 (dead after GEMM1)
  short* W1t = (short*)alloc((size_t)H_ * D_ * 2);  // W1^T bf16 [H][D]
  short* Hb  = (short*)alloc((size_t)M_ * H_ * 2);  // h bf16
  short* W2t = (short*)alloc((size_t)R_ * H_ * 2);  // W2^T bf16 [R][H]
  short* Tb  = (short*)alloc((size_t)M_ * R_ * 2);  // t bf16
  float* Sq  = (float*)alloc((size_t)M_ * 4);       // row norms f32
  // split-K partials alias the dead Xb region: 4*M*R*4 B == M*D*2 B exactly
  float* P   = (float*)Xb;

  k_prep<<<CONV_BLKS + T1B + T2B, 256, 0, stream>>>(X, W1, W2, Xb, W1t, W2t);
  k_gemm1<<<dim3((M_ / 128) * (H_ / 128)), 256, 0, stream>>>(Xb, W1t, b1, Hb);
  k_gemm2_splitk<<<dim3(1, M_ / 128, 4), 256, 0, stream>>>(Hb, W2t, P);
  k_reduce2<<<M_ / 4, 256, 0, stream>>>(P, b2, Tb, Sq);
  k_pairwise<<<dim3(L_ / 128, L_ / 128, B_), 256, 0, stream>>>(Tb, Sq, out);
}

// Round 5
// 199.458 us; speedup vs baseline: 1.1473x; 1.0247x over previous
//
#include <hip/hip_runtime.h>
#include <stdint.h>

#define B_ 16
#define L_ 1024
#define D_ 1024
#define H_ 1024
#define R_ 128
#define M_ (B_ * L_) /* 16384 */

using f32x4  = __attribute__((ext_vector_type(4))) float;
using bf16x8 = __attribute__((ext_vector_type(8))) short;

__device__ __forceinline__ short f2bf(float f) {
  uint32_t u = __builtin_bit_cast(uint32_t, f);
  u = (u + 0x7FFFu + ((u >> 16) & 1u)) >> 16;   // RNE
  return (short)(uint16_t)u;
}
__device__ __forceinline__ float bf2f(uint16_t h) {
  return __builtin_bit_cast(float, (uint32_t)h << 16);
}

__device__ __forceinline__ uint32_t lds_addr(const short* p) {
  return (uint32_t)(uintptr_t)(const __attribute__((address_space(3))) short*)p;
}

// immediate-offset LDS read: compile-time offset -> zero per-read VALU addr math.
// pairs with explicit lgkmcnt(0) + sched_barrier(0) before MFMA use (rule #18).
template <int OFF>
__device__ __forceinline__ bf16x8 lds_read_off(uint32_t addr) {
  bf16x8 r;
  asm volatile("ds_read_b128 %0, %1 offset:%2" : "=v"(r) : "v"(addr), "n"(OFF));
  return r;
}

// ---------------- fused prep: X f32->bf16 + W1^T + W2^T -----------------------
#define CONV_BLKS 8192   /* M_*D_/2048 */
#define T1B 256          /* (H_/64)*(D_/64) */
#define T2B 32           /* (R_/64)*(H_/64) */
__global__ void k_prep(const float* __restrict__ X, const float* __restrict__ W1,
                       const float* __restrict__ W2, short* __restrict__ Xb,
                       short* __restrict__ W1t, short* __restrict__ W2t) {
  __shared__ float s[64][65];
  const int b = blockIdx.x;
  if (b < CONV_BLKS) {
    size_t i = ((size_t)b * 256 + threadIdx.x) * 8;
    float4 a = *(const float4*)(X + i);
    float4 c = *(const float4*)(X + i + 4);
    union { short sh[8]; bf16x8 v; } o;
    o.sh[0] = f2bf(a.x); o.sh[1] = f2bf(a.y); o.sh[2] = f2bf(a.z); o.sh[3] = f2bf(a.w);
    o.sh[4] = f2bf(c.x); o.sh[5] = f2bf(c.y); o.sh[6] = f2bf(c.z); o.sh[7] = f2bf(c.w);
    *(bf16x8*)(Xb + i) = o.v;
    return;
  }
  const float* in; short* out; int K, N, bx, by;
  if (b < CONV_BLKS + T1B) {
    int t = b - CONV_BLKS; in = W1; out = W1t; K = D_; N = H_; bx = t & 15; by = t >> 4;
  } else {
    int t = b - CONV_BLKS - T1B; in = W2; out = W2t; K = H_; N = R_; bx = t & 1; by = t >> 1;
  }
  const int n0 = bx * 64, k0 = by * 64;
  const int tx = threadIdx.x & 63, tq = threadIdx.x >> 6;
#pragma unroll
  for (int j = 0; j < 16; ++j) {
    int r = j * 4 + tq;
    s[r][tx] = in[(size_t)(k0 + r) * N + (n0 + tx)];
  }
  __syncthreads();
#pragma unroll
  for (int j = 0; j < 16; ++j) {
    int r = j * 4 + tq;
    out[(size_t)(n0 + r) * K + (k0 + tx)] = f2bf(s[tx][r]);
  }
}

// ---- shared 128x128-tile MFMA loop: dbuf + counted vmcnt + T2 slot-swizzle ---
// LDS logical layout: [128 rows][4 slots x 8 bf16]; physical slot = slot^(row&3)
// (involution within the 64-B row). Staging keeps LDS dest LINEAR and pre-
// swizzles the GLOBAL source slot (rule #21); reads XOR the slot. 8-way -> 4-way.
// 2x-unrolled K loop makes the dbuf index compile-time -> immediate-offset reads.
__device__ __forceinline__ void gemm_body_128_db(const short* __restrict__ Ap,
                                                 const short* __restrict__ Bp,
                                                 int ld, int kSteps,
                                                 short* As, short* Bs,
                                                 f32x4 (&acc)[4][4]) {
  const int tid = threadIdx.x, lane = tid & 63, wave = tid >> 6;
  const int wr = wave >> 1, wc = wave & 1;
  const int lrow = lane & 15;
  const int srow = lane >> 2;                       // staging row within chunk
  const int skc  = (((lane & 3) ^ (srow & 3)) * 8); // pre-swizzled source slot
  const int rslot = (lane >> 4) ^ (lane & 3);       // physical slot on read
  const uint32_t aBase = lds_addr(As) + (uint32_t)((wr * 64 + lrow) * 64 + rslot * 16);
  const uint32_t bBase = lds_addr(Bs) + (uint32_t)((wc * 64 + lrow) * 64 + rslot * 16);

  auto STAGE = [&](int ks, int d) {
    const int k0 = ks * 32;
#pragma unroll
    for (int c = 0; c < 2; ++c) {
      const int chunk = wave * 2 + c;
      const int row = chunk * 16 + srow;
      __builtin_amdgcn_global_load_lds(
          (const __attribute__((address_space(1))) void*)(Ap + (size_t)row * ld + (k0 + skc)),
          (__attribute__((address_space(3))) void*)(As + d * 4096 + chunk * 512 + lane * 8), 16, 0, 0);
      __builtin_amdgcn_global_load_lds(
          (const __attribute__((address_space(1))) void*)(Bp + (size_t)row * ld + (k0 + skc)),
          (__attribute__((address_space(3))) void*)(Bs + d * 4096 + chunk * 512 + lane * 8), 16, 0, 0);
    }
  };

#define GEMM_PHASE(KS_NEXT, STAGE_DST, CUROFF)                                 \
  {                                                                            \
    const int ksn = (KS_NEXT);                                                 \
    if (ksn < kSteps) {                                                        \
      STAGE(ksn, STAGE_DST);                                                   \
      asm volatile("s_waitcnt vmcnt(4)" ::: "memory");                         \
    } else {                                                                   \
      asm volatile("s_waitcnt vmcnt(0)" ::: "memory");                         \
    }                                                                          \
    __builtin_amdgcn_s_barrier();                                              \
    bf16x8 af[4], bfr[4];                                                      \
    af[0]  = lds_read_off<(CUROFF) + 0>(aBase);                                \
    af[1]  = lds_read_off<(CUROFF) + 1024>(aBase);                             \
    af[2]  = lds_read_off<(CUROFF) + 2048>(aBase);                             \
    af[3]  = lds_read_off<(CUROFF) + 3072>(aBase);                             \
    bfr[0] = lds_read_off<(CUROFF) + 0>(bBase);                                \
    bfr[1] = lds_read_off<(CUROFF) + 1024>(bBase);                             \
    bfr[2] = lds_read_off<(CUROFF) + 2048>(bBase);                             \
    bfr[3] = lds_read_off<(CUROFF) + 3072>(bBase);                             \
    asm volatile("s_waitcnt lgkmcnt(0)" ::: "memory");                         \
    __builtin_amdgcn_sched_barrier(0);                                         \
    __builtin_amdgcn_s_setprio(1);                                             \
    _Pragma("unroll") for (int m = 0; m < 4; ++m)                              \
      _Pragma("unroll") for (int n = 0; n < 4; ++n)                            \
        acc[m][n] = __builtin_amdgcn_mfma_f32_16x16x32_bf16(af[m], bfr[n],     \
                                                            acc[m][n], 0, 0, 0); \
    __builtin_amdgcn_s_setprio(0);                                             \
    asm volatile("" ::: "memory");                                             \
    __builtin_amdgcn_s_barrier();                                              \
  }

  STAGE(0, 0);
  for (int ks = 0; ks < kSteps; ks += 2) {   // kSteps is even for all callers
    GEMM_PHASE(ks + 1, 1, 0)
    GEMM_PHASE(ks + 2, 0, 8192)
  }
#undef GEMM_PHASE
}

// -------- GEMM1: M=16384 N=1024 K=1024, XCD-swizzled grid (1024 blocks) -------
__global__ __launch_bounds__(256)
void k_gemm1(const short* __restrict__ A, const short* __restrict__ Bt,
             const float* __restrict__ bias, short* __restrict__ C) {
  __shared__ __align__(16) short As[2 * 4096];
  __shared__ __align__(16) short Bs[2 * 4096];
  const int b = blockIdx.x;
  const int xcd = b & 7, seq = b >> 3;
  const int g = xcd + ((seq >> 6) << 3);   // 0..15
  const int i = seq & 63;
  const int m0 = (g * 8 + (i >> 3)) * 128;
  const int n0 = (i & 7) * 128;

  f32x4 acc[4][4] = {};
  gemm_body_128_db(A + (size_t)m0 * D_, Bt + (size_t)n0 * D_, D_, D_ / 32, As, Bs, acc);

  const int lane = threadIdx.x & 63, wave = threadIdx.x >> 6;
  const int wr = wave >> 1, wc = wave & 1;
  const int rbase = m0 + wr * 64 + (lane >> 4) * 4;
  const int cbase = n0 + wc * 64 + (lane & 15);
#pragma unroll
  for (int n = 0; n < 4; ++n) {
    const int col = cbase + n * 16;
    const float bn = bias[col];
#pragma unroll
    for (int m = 0; m < 4; ++m) {
      const int row = rbase + m * 16;
#pragma unroll
      for (int r = 0; r < 4; ++r) {
        float v = acc[m][n][r] + bn;
        C[(size_t)(row + r) * H_ + col] = f2bf(fmaxf(v, 0.f));
      }
    }
  }
}

// -------- GEMM2 split-K=4: M=16384 N=128 K=1024 -> f32 partials ---------------
__global__ __launch_bounds__(256)
void k_gemm2_splitk(const short* __restrict__ A, const short* __restrict__ Bt,
                    float* __restrict__ P) {
  __shared__ __align__(16) short As[2 * 4096];
  __shared__ __align__(16) short Bs[2 * 4096];
  const int m0 = blockIdx.y * 128;
  const int s  = blockIdx.z;
  const int kOff = s * (H_ / 4);

  f32x4 acc[4][4] = {};
  gemm_body_128_db(A + (size_t)m0 * H_ + kOff, Bt + kOff, H_, (H_ / 4) / 32, As, Bs, acc);

  const int lane = threadIdx.x & 63, wave = threadIdx.x >> 6;
  const int wr = wave >> 1, wc = wave & 1;
  const int rbase = wr * 64 + (lane >> 4) * 4;
  const int cbase = wc * 64 + (lane & 15);
  float* Ps = P + (size_t)s * M_ * R_ + (size_t)m0 * R_;
#pragma unroll
  for (int m = 0; m < 4; ++m)
#pragma unroll
    for (int r = 0; r < 4; ++r)
#pragma unroll
      for (int n = 0; n < 4; ++n)
        Ps[(size_t)(rbase + m * 16 + r) * R_ + cbase + n * 16] = acc[m][n][r];
}

// -------- reduce split-K partials + bias + ReLU -> bf16 T, fused row norms ----
__global__ void k_reduce2(const float* __restrict__ P, const float* __restrict__ b2,
                          short* __restrict__ T, float* __restrict__ sq) {
  const int row  = blockIdx.x * 4 + (threadIdx.x >> 6);
  const int lane = threadIdx.x & 63;
  const int c0 = lane * 2;
  float s0 = 0.f, s1 = 0.f;
#pragma unroll
  for (int s = 0; s < 4; ++s) {
    const float2 v = *(const float2*)(P + ((size_t)s * M_ + row) * R_ + c0);
    s0 += v.x; s1 += v.y;
  }
  float v0 = fmaxf(s0 + b2[c0], 0.f);
  float v1 = fmaxf(s1 + b2[c0 + 1], 0.f);
  uint32_t pk = (uint32_t)(uint16_t)f2bf(v0) | ((uint32_t)(uint16_t)f2bf(v1) << 16);
  *(uint32_t*)(T + (size_t)row * R_ + c0) = pk;
  float q = v0 * v0 + v1 * v1;
#pragma unroll
  for (int o = 32; o >= 1; o >>= 1) q += __shfl_xor(q, o, 64);
  if (lane == 0) sq[row] = q;
}

// -------- per-batch pairwise: out = max(sq_i + sq_j - 2*T_i.T_j, 0) -----------
__global__ __launch_bounds__(256)
void k_pairwise(const short* __restrict__ T, const float* __restrict__ sq,
                float* __restrict__ out) {
  __shared__ __align__(16) short As[2 * 4096];
  __shared__ __align__(16) short Bs[2 * 4096];
  const int b = blockIdx.z;
  const short* Tb  = T  + (size_t)b * L_ * R_;
  const float* sqb = sq + (size_t)b * L_;
  const int m0 = blockIdx.y * 128, n0 = blockIdx.x * 128;

  f32x4 acc[4][4] = {};
  gemm_body_128_db(Tb + (size_t)m0 * R_, Tb + (size_t)n0 * R_, R_, R_ / 32, As, Bs, acc);

  const int lane = threadIdx.x & 63, wave = threadIdx.x >> 6;
  const int wr = wave >> 1, wc = wave & 1;
  const int rbase = m0 + wr * 64 + (lane >> 4) * 4;
  const int cbase = n0 + wc * 64 + (lane & 15);
  float sqj[4];
#pragma unroll
  for (int n = 0; n < 4; ++n) sqj[n] = sqb[cbase + n * 16];
#pragma unroll
  for (int m = 0; m < 4; ++m) {
#pragma unroll
    for (int r = 0; r < 4; ++r) {
      const int row = rbase + m * 16 + r;
      const float sqi = sqb[row];
      float* orow = out + ((size_t)b * L_ + row) * L_;
#pragma unroll
      for (int n = 0; n < 4; ++n) {
        float d = sqi + sqj[n] - 2.0f * acc[m][n][r];
        orow[cbase + n * 16] = fmaxf(d, 0.f);
      }
    }
  }
}

extern "C" void kernel_launch(void* const* d_in, const int* in_sizes, int n_in,
                              void* d_out, int out_size, void* d_ws, size_t ws_size,
                              hipStream_t stream) {
  const float* X  = (const float*)d_in[0];
  const float* W1 = (const float*)d_in[1];
  const float* b1 = (const float*)d_in[2];
  const float* W2 = (const float*)d_in[3];
  const float* b2 = (const float*)d_in[4];
  float* out = (float*)d_out;

  char* ws = (char*)d_ws;
  size_t off = 0;
  auto alloc = [&](size_t bytes) {
    char* p = ws + off;
    off += (bytes + 255) & ~(size_t)255;
    return p;
  };
  short* Xb  = (short*)alloc((size_t)M_ * D_ * 2);  // X bf16 (dead after GEMM1)
  short* W1t = (short*)alloc((size_t)H_ * D_ * 2);  // W1^T bf16 [H][D]
  short* Hb  = (short*)alloc((size_t)M_ * H_ * 2);  // h bf16
  short* W2t = (short*)alloc((size_t)R_ * H_ * 2);  // W2^T bf16 [R][H]
  short* Tb  = (short*)alloc((size_t)M_ * R_ * 2);  // t bf16
  float* Sq  = (float*)alloc((size_t)M_ * 4);       // row norms f32
  // split-K partials alias the dead Xb region: 4*M*R*4 B == M*D*2 B exactly
  float* P   = (float*)Xb;

  k_prep<<<CONV_BLKS + T1B + T2B, 256, 0, stream>>>(X, W1, W2, Xb, W1t, W2t);
  k_gemm1<<<dim3((M_ / 128) * (H_ / 128)), 256, 0, stream>>>(Xb, W1t, b1, Hb);
  k_gemm2_splitk<<<dim3(1, M_ / 128, 4), 256, 0, stream>>>(Hb, W2t, P);
  k_reduce2<<<M_ / 4, 256, 0, stream>>>(P, b2, Tb, Sq);
  k_pairwise<<<dim3(L_ / 128, L_ / 128, B_), 256, 0, stream>>>(Tb, Sq, out);
}